// Round 2
// baseline (4592.219 us; speedup 1.0000x reference)
//
#include <hip/hip_runtime.h>
#include <math.h>

#define LN2F 0.69314718055994531f

typedef _Float16 v8hf __attribute__((ext_vector_type(8)));
typedef float    v4f  __attribute__((ext_vector_type(4)));

__device__ __forceinline__ float ssp_f(float x) {
    return fmaxf(x, 0.f) + log1pf(expf(-fabsf(x))) - LN2F;
}

// ---------------------------------------------------------------------------
// Prep: convert weights to f16 in MFMA-B-fragment order.
// Fragment layout for a 128xK (K=128 or padded-64) row-major W:
//   frag[((nt*KS + ks)*64 + lane)*8 + i] = W[nt*16 + (lane&15)][ks*32 + (lane>>4)*8 + i]
// w1: 128x50 (K padded to 64, KS=2). w2/l1w/l2w/lw: 128x128 (KS=4).
// ---------------------------------------------------------------------------
__global__ __launch_bounds__(256)
void prep_kernel(const float* __restrict__ w1, const float* __restrict__ w2,
                 const float* __restrict__ l1w, const float* __restrict__ l2w,
                 const float* __restrict__ lw,
                 _Float16* __restrict__ w1f, _Float16* __restrict__ w2f,
                 _Float16* __restrict__ l1f, _Float16* __restrict__ l2f,
                 _Float16* __restrict__ lwf)
{
    int idx = blockIdx.x * 256 + threadIdx.x;
    if (idx < 8192) {  // w1f
        int i = idx & 7, lane = (idx >> 3) & 63, ks = (idx >> 9) & 1, nt = idx >> 10;
        int r = nt * 16 + (lane & 15);
        int k = ks * 32 + (lane >> 4) * 8 + i;
        w1f[idx] = (k < 50) ? (_Float16)w1[r * 50 + k] : (_Float16)0.f;
        return;
    }
    int o = idx - 8192;
    if (o >= 4 * 16384) return;
    int which = o >> 14;
    int p = o & 16383;
    int i = p & 7, lane = (p >> 3) & 63, ks = (p >> 9) & 3, nt = p >> 11;
    int r = nt * 16 + (lane & 15);
    int k = ks * 32 + (lane >> 4) * 8 + i;
    const float* src = (which == 0) ? w2 : (which == 1) ? l1w : (which == 2) ? l2w : lw;
    _Float16* dst   = (which == 0) ? w2f : (which == 1) ? l1f : (which == 2) ? l2f : lwf;
    dst[p] = (_Float16)src[r * 128 + k];
}

// ---------------------------------------------------------------------------
// Y = act(X @ W^T + bias) via f16 MFMA, f32 accumulate. X: M x 128 f32,
// Wf: fragment-ordered f16 (see prep). Block 256 = 4 waves, 16 rows/wave.
// No LDS; B-fragments stream from L1/L2. A-frag: lane m=lane&15, k=quad*8+i.
// D: row = quad*4+r, col = lane&15 (per 16-col tile nt).
// ---------------------------------------------------------------------------
template<bool SSP, bool BIAS>
__global__ __launch_bounds__(256)
void mfma_lin_kernel(const float* __restrict__ X, const _Float16* __restrict__ Wf,
                     const float* __restrict__ bias, float* __restrict__ Y, int M)
{
    const int tid = threadIdx.x;
    const int lane = tid & 63;
    const int wv = tid >> 6;
    const int l15 = lane & 15;
    const int quad = lane >> 4;
    const int mb = blockIdx.x * 64 + wv * 16;

    const int mA = (mb + l15 < M) ? (mb + l15) : (M - 1);
    v8hf a[4];
    #pragma unroll
    for (int ks = 0; ks < 4; ++ks) {
        const float4* xp = (const float4*)&X[(size_t)mA * 128 + ks * 32 + quad * 8];
        float4 x0 = xp[0], x1 = xp[1];
        v8hf t = {(_Float16)x0.x, (_Float16)x0.y, (_Float16)x0.z, (_Float16)x0.w,
                  (_Float16)x1.x, (_Float16)x1.y, (_Float16)x1.z, (_Float16)x1.w};
        a[ks] = t;
    }

    v4f acc[8];
    #pragma unroll
    for (int nt = 0; nt < 8; ++nt) {
        acc[nt] = (v4f){0.f, 0.f, 0.f, 0.f};
        #pragma unroll
        for (int ks = 0; ks < 4; ++ks) {
            const v8hf b = *(const v8hf*)&Wf[((nt * 4 + ks) * 64 + lane) * 8];
            acc[nt] = __builtin_amdgcn_mfma_f32_16x16x32_f16(a[ks], b, acc[nt], 0, 0, 0);
        }
    }

    const int row0 = mb + quad * 4;
    #pragma unroll
    for (int nt = 0; nt < 8; ++nt) {
        const int col = nt * 16 + l15;
        const float bj = BIAS ? bias[col] : 0.f;
        #pragma unroll
        for (int r = 0; r < 4; ++r) {
            int row = row0 + r;
            if (row < M) {
                float v = acc[nt][r] + bj;
                Y[(size_t)row * 128 + col] = SSP ? ssp_f(v) : v;
            }
        }
    }
}

// ---------------------------------------------------------------------------
// Fused edge kernel, 64 edges/block, 256 threads (4 waves, 16 edges/wave).
//   stage1: u = ssp(attr @ W1^T + b1)   (MFMA, K padded 64; B-frags from global)
//   stage2: WfC = (u @ W2^T + b2) * C   (MFMA, K=128) -> f16 into LDS (reuse Uh)
//   epilogue: lane owns 1 edge x 32 cols: contiguous h-gather + atomic scatter.
// Uh is wave-private (each wave writes/reads only its own 16 rows) -> no
// barrier needed after staging barrier; in-order per-wave DS ops suffice.
// ---------------------------------------------------------------------------
__global__ __launch_bounds__(256)
void edge_kernel(const float* __restrict__ attr,  // E x 50
                 const float* __restrict__ ew,    // E
                 const int* __restrict__ srcI,
                 const int* __restrict__ dstI,
                 const _Float16* __restrict__ w1f,
                 const _Float16* __restrict__ w2f,
                 const float* __restrict__ b1,
                 const float* __restrict__ b2,
                 const float* __restrict__ h,     // N x 128
                 float* __restrict__ agg,         // N x 128 (zeroed)
                 int E)
{
    __shared__ __align__(16) _Float16 Ah[64 * 72];
    __shared__ __align__(16) _Float16 Uh[64 * 136];
    __shared__ float b1S[128], b2S[128], Cs[64];
    __shared__ int sS[64], dS[64];

    const int tid = threadIdx.x;
    const int e_base = blockIdx.x * 64;

    for (int idx = tid; idx < 64 * 64; idx += 256) {
        int r = idx >> 6, g = idx & 63;
        int e = e_base + r;
        float v = (g < 50 && e < E) ? attr[(size_t)e * 50 + g] : 0.f;
        Ah[r * 72 + g] = (_Float16)v;
    }
    if (tid < 128) { b1S[tid] = b1[tid]; b2S[tid] = b2[tid]; }
    if (tid < 64) {
        int e = e_base + tid;
        if (e < E) {
            Cs[tid] = 0.5f * (cosf(ew[e] * 0.31415926535897932f) + 1.f);
            sS[tid] = srcI[e]; dS[tid] = dstI[e];
        } else { Cs[tid] = 0.f; sS[tid] = 0; dS[tid] = 0; }
    }
    __syncthreads();

    const int lane = tid & 63, wv = tid >> 6;
    const int m0 = wv * 16, l15 = lane & 15, quad = lane >> 4;

    // ---- stage 1 ----
    const v8hf a0 = *(const v8hf*)&Ah[(m0 + l15) * 72 + quad * 8];
    const v8hf a1 = *(const v8hf*)&Ah[(m0 + l15) * 72 + 32 + quad * 8];
    #pragma unroll
    for (int nt = 0; nt < 8; ++nt) {
        v4f acc = {0.f, 0.f, 0.f, 0.f};
        const v8hf bA = *(const v8hf*)&w1f[((nt * 2 + 0) * 64 + lane) * 8];
        const v8hf bB = *(const v8hf*)&w1f[((nt * 2 + 1) * 64 + lane) * 8];
        acc = __builtin_amdgcn_mfma_f32_16x16x32_f16(a0, bA, acc, 0, 0, 0);
        acc = __builtin_amdgcn_mfma_f32_16x16x32_f16(a1, bB, acc, 0, 0, 0);
        const float bj = b1S[nt * 16 + l15];
        #pragma unroll
        for (int r = 0; r < 4; ++r)
            Uh[(m0 + quad * 4 + r) * 136 + nt * 16 + l15] = (_Float16)ssp_f(acc[r] + bj);
    }

    // ---- stage 2 (same-wave LDS dep; compiler waitcnt orders it) ----
    v8hf ua[4];
    #pragma unroll
    for (int ks = 0; ks < 4; ++ks)
        ua[ks] = *(const v8hf*)&Uh[(m0 + l15) * 136 + ks * 32 + quad * 8];
    float cC[4];
    #pragma unroll
    for (int r = 0; r < 4; ++r) cC[r] = Cs[m0 + quad * 4 + r];

    #pragma unroll
    for (int nt = 0; nt < 8; ++nt) {
        v4f acc = {0.f, 0.f, 0.f, 0.f};
        #pragma unroll
        for (int ks = 0; ks < 4; ++ks) {
            const v8hf b = *(const v8hf*)&w2f[((nt * 4 + ks) * 64 + lane) * 8];
            acc = __builtin_amdgcn_mfma_f32_16x16x32_f16(ua[ks], b, acc, 0, 0, 0);
        }
        const float bj = b2S[nt * 16 + l15];
        #pragma unroll
        for (int r = 0; r < 4; ++r)
            Uh[(m0 + quad * 4 + r) * 136 + nt * 16 + l15] =
                (_Float16)((acc[r] + bj) * cC[r]);
    }

    // ---- epilogue: lane -> (edge el, cols c0..c0+32) ----
    const int el = m0 + (lane >> 2);
    const int c0 = (lane & 3) * 32;
    if (e_base + el < E) {
        const float* hp = h + (size_t)sS[el] * 128 + c0;
        float* ap = agg + (size_t)dS[el] * 128 + c0;
        #pragma unroll
        for (int t = 0; t < 4; ++t) {
            const v8hf wv8 = *(const v8hf*)&Uh[el * 136 + c0 + t * 8];
            const float4 h0 = *(const float4*)&hp[t * 8];
            const float4 h1 = *(const float4*)&hp[t * 8 + 4];
            atomicAdd(&ap[t * 8 + 0], (float)wv8[0] * h0.x);
            atomicAdd(&ap[t * 8 + 1], (float)wv8[1] * h0.y);
            atomicAdd(&ap[t * 8 + 2], (float)wv8[2] * h0.z);
            atomicAdd(&ap[t * 8 + 3], (float)wv8[3] * h0.w);
            atomicAdd(&ap[t * 8 + 4], (float)wv8[4] * h1.x);
            atomicAdd(&ap[t * 8 + 5], (float)wv8[5] * h1.y);
            atomicAdd(&ap[t * 8 + 6], (float)wv8[6] * h1.z);
            atomicAdd(&ap[t * 8 + 7], (float)wv8[7] * h1.w);
        }
    }
}

extern "C" void kernel_launch(void* const* d_in, const int* in_sizes, int n_in,
                              void* d_out, int out_size, void* d_ws, size_t ws_size,
                              hipStream_t stream)
{
    const float* x   = (const float*)d_in[0];
    const int*   ei  = (const int*)  d_in[1];
    const float* ew  = (const float*)d_in[2];
    const float* ea  = (const float*)d_in[3];
    const float* w1  = (const float*)d_in[4];
    const float* b1  = (const float*)d_in[5];
    const float* w2  = (const float*)d_in[6];
    const float* b2  = (const float*)d_in[7];
    const float* l1w = (const float*)d_in[8];
    const float* l2w = (const float*)d_in[9];
    const float* l2b = (const float*)d_in[10];
    const float* lw  = (const float*)d_in[11];
    const float* lb  = (const float*)d_in[12];

    const int N = in_sizes[0] / 128;   // 40000
    const int E = in_sizes[2];         // 640000

    float* hbuf = (float*)d_ws;                       // N*128 f32
    float* agg  = hbuf + (size_t)N * 128;             // N*128 f32
    _Float16* w1f = (_Float16*)(agg + (size_t)N * 128);   // 8192
    _Float16* w2f = w1f + 8192;                       // 16384
    _Float16* l1f = w2f + 16384;
    _Float16* l2f = l1f + 16384;
    _Float16* lwf = l2f + 16384;

    const int nb = (N + 63) / 64;

    // weights -> f16 fragment order (73728 elems)
    prep_kernel<<<288, 256, 0, stream>>>(w1, w2, l1w, l2w, lw,
                                         w1f, w2f, l1f, l2f, lwf);
    hipMemsetAsync(agg, 0, (size_t)N * 128 * sizeof(float), stream);
    // h = x @ lin1_w^T
    mfma_lin_kernel<false, false><<<nb, 256, 0, stream>>>(x, l1f, nullptr, hbuf, N);
    // fused filter-MLP + envelope + gather + scatter
    edge_kernel<<<(E + 63) / 64, 256, 0, stream>>>(ea, ew, ei, ei + E,
                                                   w1f, w2f, b1, b2, hbuf, agg, E);
    // s = ssp(agg @ lin2_w^T + lin2_b)
    mfma_lin_kernel<true, true><<<nb, 256, 0, stream>>>(agg, l2f, l2b, hbuf, N);
    // out = s @ lin_w^T + lin_b
    mfma_lin_kernel<false, true><<<nb, 256, 0, stream>>>(hbuf, lwf, lb, (float*)d_out, N);
}

// Round 3
// 624.435 us; speedup vs baseline: 7.3542x; 7.3542x over previous
//
#include <hip/hip_runtime.h>
#include <math.h>

#define LN2F 0.69314718055994531f

typedef _Float16 v8hf __attribute__((ext_vector_type(8)));
typedef float    v4f  __attribute__((ext_vector_type(4)));

__device__ __forceinline__ float ssp_f(float x) {
    return fmaxf(x, 0.f) + log1pf(expf(-fabsf(x))) - LN2F;
}

// ---------------------------------------------------------------------------
// Prep: weights -> f16, MFMA-B-fragment order.
//   frag[((nt*KS+ks)*64 + lane)*8 + i] = W[nt*16+(lane&15)][ks*32+(lane>>4)*8+i]
// w1: 128x50 (K padded 64, KS=2); others 128x128 (KS=4).
// ---------------------------------------------------------------------------
__global__ __launch_bounds__(256)
void prep_kernel(const float* __restrict__ w1, const float* __restrict__ w2,
                 const float* __restrict__ l1w, const float* __restrict__ l2w,
                 const float* __restrict__ lw,
                 _Float16* __restrict__ w1f, _Float16* __restrict__ w2f,
                 _Float16* __restrict__ l1f, _Float16* __restrict__ l2f,
                 _Float16* __restrict__ lwf)
{
    int idx = blockIdx.x * 256 + threadIdx.x;
    if (idx < 8192) {  // w1f
        int i = idx & 7, lane = (idx >> 3) & 63, ks = (idx >> 9) & 1, nt = idx >> 10;
        int r = nt * 16 + (lane & 15);
        int k = ks * 32 + (lane >> 4) * 8 + i;
        w1f[idx] = (k < 50) ? (_Float16)w1[r * 50 + k] : (_Float16)0.f;
        return;
    }
    int o = idx - 8192;
    if (o >= 4 * 16384) return;
    int which = o >> 14;
    int p = o & 16383;
    int i = p & 7, lane = (p >> 3) & 63, ks = (p >> 9) & 3, nt = p >> 11;
    int r = nt * 16 + (lane & 15);
    int k = ks * 32 + (lane >> 4) * 8 + i;
    const float* src = (which == 0) ? w2 : (which == 1) ? l1w : (which == 2) ? l2w : lw;
    _Float16* dst   = (which == 0) ? w2f : (which == 1) ? l1f : (which == 2) ? l2f : lwf;
    dst[p] = (_Float16)src[r * 128 + k];
}

// ---------------------------------------------------------------------------
// h = X @ W^T (no bias, no act). f16 MFMA, B-frags from global (L1/L2).
// Block 256 = 4 waves x 16 rows.
// ---------------------------------------------------------------------------
__global__ __launch_bounds__(256)
void h_gemm_kernel(const float* __restrict__ X, const _Float16* __restrict__ Wf,
                   float* __restrict__ Y, int M)
{
    const int tid = threadIdx.x, lane = tid & 63, wv = tid >> 6;
    const int l15 = lane & 15, quad = lane >> 4;
    const int mb = blockIdx.x * 64 + wv * 16;

    const int mA = (mb + l15 < M) ? (mb + l15) : (M - 1);
    v8hf a[4];
    #pragma unroll
    for (int ks = 0; ks < 4; ++ks) {
        const float4* xp = (const float4*)&X[(size_t)mA * 128 + ks * 32 + quad * 8];
        float4 x0 = xp[0], x1 = xp[1];
        v8hf t = {(_Float16)x0.x, (_Float16)x0.y, (_Float16)x0.z, (_Float16)x0.w,
                  (_Float16)x1.x, (_Float16)x1.y, (_Float16)x1.z, (_Float16)x1.w};
        a[ks] = t;
    }
    #pragma unroll
    for (int nt = 0; nt < 8; ++nt) {
        v4f acc = {0.f, 0.f, 0.f, 0.f};
        #pragma unroll
        for (int ks = 0; ks < 4; ++ks) {
            const v8hf b = *(const v8hf*)&Wf[((nt * 4 + ks) * 64 + lane) * 8];
            acc = __builtin_amdgcn_mfma_f32_16x16x32_f16(a[ks], b, acc, 0, 0, 0);
        }
        const int col = nt * 16 + l15;
        #pragma unroll
        for (int r = 0; r < 4; ++r) {
            int row = mb + quad * 4 + r;
            if (row < M) Y[(size_t)row * 128 + col] = acc[nt == nt ? r : r]; // acc[r]
        }
    }
}

// ---------------------------------------------------------------------------
// Fused tail: out = ssp(agg @ l2^T + l2b) @ lw^T + lb.
// s goes through LDS (D-layout -> A-layout), wave-private rows.
// ---------------------------------------------------------------------------
__global__ __launch_bounds__(256)
void fused_out_kernel(const float* __restrict__ agg, const _Float16* __restrict__ l2f,
                      const float* __restrict__ l2b, const _Float16* __restrict__ lwf,
                      const float* __restrict__ lb, float* __restrict__ out, int M)
{
    __shared__ __align__(16) _Float16 Sh[64 * 138];
    const int tid = threadIdx.x, lane = tid & 63, wv = tid >> 6;
    const int l15 = lane & 15, quad = lane >> 4;
    const int m0 = wv * 16;           // local row base of this wave
    const int gbase = blockIdx.x * 64;

    const int mA = (gbase + m0 + l15 < M) ? (gbase + m0 + l15) : (M - 1);
    v8hf a[4];
    #pragma unroll
    for (int ks = 0; ks < 4; ++ks) {
        const float4* xp = (const float4*)&agg[(size_t)mA * 128 + ks * 32 + quad * 8];
        float4 x0 = xp[0], x1 = xp[1];
        v8hf t = {(_Float16)x0.x, (_Float16)x0.y, (_Float16)x0.z, (_Float16)x0.w,
                  (_Float16)x1.x, (_Float16)x1.y, (_Float16)x1.z, (_Float16)x1.w};
        a[ks] = t;
    }
    #pragma unroll
    for (int nt = 0; nt < 8; ++nt) {
        v4f acc = {0.f, 0.f, 0.f, 0.f};
        #pragma unroll
        for (int ks = 0; ks < 4; ++ks) {
            const v8hf b = *(const v8hf*)&l2f[((nt * 4 + ks) * 64 + lane) * 8];
            acc = __builtin_amdgcn_mfma_f32_16x16x32_f16(a[ks], b, acc, 0, 0, 0);
        }
        const float bj = l2b[nt * 16 + l15];
        #pragma unroll
        for (int r = 0; r < 4; ++r)
            Sh[(m0 + quad * 4 + r) * 138 + nt * 16 + l15] = (_Float16)ssp_f(acc[r] + bj);
    }
    // wave-private rows: per-wave in-order DS ops, no barrier needed
    v8hf ua[4];
    #pragma unroll
    for (int ks = 0; ks < 4; ++ks)
        ua[ks] = *(const v8hf*)&Sh[(m0 + l15) * 138 + ks * 32 + quad * 8];

    #pragma unroll
    for (int nt = 0; nt < 8; ++nt) {
        v4f acc = {0.f, 0.f, 0.f, 0.f};
        #pragma unroll
        for (int ks = 0; ks < 4; ++ks) {
            const v8hf b = *(const v8hf*)&lwf[((nt * 4 + ks) * 64 + lane) * 8];
            acc = __builtin_amdgcn_mfma_f32_16x16x32_f16(ua[ks], b, acc, 0, 0, 0);
        }
        const int col = nt * 16 + l15;
        const float bj = lb[col];
        #pragma unroll
        for (int r = 0; r < 4; ++r) {
            int row = gbase + m0 + quad * 4 + r;
            if (row < M) out[(size_t)row * 128 + col] = acc[r] + bj;
        }
    }
}

// ---------------------------------------------------------------------------
// Fused edge kernel. 64 edges/block, 256 threads (4 waves x 16 edges).
//   stage1: u = ssp(attr @ W1^T + b1)        (MFMA K=64; B-frags from global)
//   stage2: Wf = (u @ W2^T + b2) * C         (MFMA K=128, no LDS round-trip)
//   epilogue in D-layout: 16 consecutive lanes cover 16 consecutive cols of
//   ONE edge-row -> 64B-coalesced gather AND 64B-coalesced atomics.
//   (Round-2 lesson: lane-scattered f32 atomics cost 32B HBM/atomic = 8x.)
// LDS strides 74/138 f16 (odd word counts -> conflict-free b128 reads).
// ---------------------------------------------------------------------------
__global__ __launch_bounds__(256, 5)
void edge_kernel(const float* __restrict__ attr,  // E x 50
                 const float* __restrict__ ew,    // E
                 const int* __restrict__ srcI,
                 const int* __restrict__ dstI,
                 const _Float16* __restrict__ w1f,
                 const _Float16* __restrict__ w2f,
                 const float* __restrict__ b1,
                 const float* __restrict__ b2,
                 const float* __restrict__ h,     // N x 128
                 float* __restrict__ agg,         // N x 128 (zeroed)
                 int E)
{
    __shared__ __align__(16) _Float16 Ah[64 * 74];
    __shared__ __align__(16) _Float16 Uh[64 * 138];
    __shared__ float b1S[128], b2S[128], Cs[64];
    __shared__ int sS[64], dS[64];

    const int tid = threadIdx.x;
    const int e_base = blockIdx.x * 64;

    for (int idx = tid; idx < 64 * 64; idx += 256) {
        int r = idx >> 6, g = idx & 63;
        int e = e_base + r;
        float v = (g < 50 && e < E) ? attr[(size_t)e * 50 + g] : 0.f;
        Ah[r * 74 + g] = (_Float16)v;
    }
    if (tid < 128) { b1S[tid] = b1[tid]; b2S[tid] = b2[tid]; }
    if (tid < 64) {
        int e = e_base + tid;
        if (e < E) {
            Cs[tid] = 0.5f * (cosf(ew[e] * 0.31415926535897932f) + 1.f);
            sS[tid] = srcI[e]; dS[tid] = dstI[e];
        } else { Cs[tid] = 0.f; sS[tid] = 0; dS[tid] = 0; }
    }
    __syncthreads();

    const int lane = tid & 63, wv = tid >> 6;
    const int m0 = wv * 16, l15 = lane & 15, quad = lane >> 4;

    // ---- stage 1 ----
    const v8hf a0 = *(const v8hf*)&Ah[(m0 + l15) * 74 + quad * 8];
    const v8hf a1 = *(const v8hf*)&Ah[(m0 + l15) * 74 + 32 + quad * 8];
    #pragma unroll
    for (int nt = 0; nt < 8; ++nt) {
        v4f acc = {0.f, 0.f, 0.f, 0.f};
        const v8hf bA = *(const v8hf*)&w1f[((nt * 2 + 0) * 64 + lane) * 8];
        const v8hf bB = *(const v8hf*)&w1f[((nt * 2 + 1) * 64 + lane) * 8];
        acc = __builtin_amdgcn_mfma_f32_16x16x32_f16(a0, bA, acc, 0, 0, 0);
        acc = __builtin_amdgcn_mfma_f32_16x16x32_f16(a1, bB, acc, 0, 0, 0);
        const float bj = b1S[nt * 16 + l15];
        #pragma unroll
        for (int r = 0; r < 4; ++r)
            Uh[(m0 + quad * 4 + r) * 138 + nt * 16 + l15] = (_Float16)ssp_f(acc[r] + bj);
    }

    // ---- stage 2 + D-layout epilogue (wave-private LDS rows, no barrier) ----
    v8hf ua[4];
    #pragma unroll
    for (int ks = 0; ks < 4; ++ks)
        ua[ks] = *(const v8hf*)&Uh[(m0 + l15) * 138 + ks * 32 + quad * 8];

    float cC[4]; const float* hrow[4]; float* arow[4]; bool val[4];
    #pragma unroll
    for (int r = 0; r < 4; ++r) {
        int el = m0 + quad * 4 + r;
        cC[r] = Cs[el];
        hrow[r] = h + (size_t)sS[el] * 128;
        arow[r] = agg + (size_t)dS[el] * 128;
        val[r] = (e_base + el) < E;
    }

    #pragma unroll
    for (int nt = 0; nt < 8; ++nt) {
        v4f acc = {0.f, 0.f, 0.f, 0.f};
        #pragma unroll
        for (int ks = 0; ks < 4; ++ks) {
            const v8hf b = *(const v8hf*)&w2f[((nt * 4 + ks) * 64 + lane) * 8];
            acc = __builtin_amdgcn_mfma_f32_16x16x32_f16(ua[ks], b, acc, 0, 0, 0);
        }
        const int col = nt * 16 + l15;
        const float bj = b2S[col];
        #pragma unroll
        for (int r = 0; r < 4; ++r) {
            if (val[r]) {
                float wf = (acc[r] + bj) * cC[r];
                atomicAdd(&arow[r][col], wf * hrow[r][col]);
            }
        }
    }
}

extern "C" void kernel_launch(void* const* d_in, const int* in_sizes, int n_in,
                              void* d_out, int out_size, void* d_ws, size_t ws_size,
                              hipStream_t stream)
{
    const float* x   = (const float*)d_in[0];
    const int*   ei  = (const int*)  d_in[1];
    const float* ew  = (const float*)d_in[2];
    const float* ea  = (const float*)d_in[3];
    const float* w1  = (const float*)d_in[4];
    const float* b1  = (const float*)d_in[5];
    const float* w2  = (const float*)d_in[6];
    const float* b2  = (const float*)d_in[7];
    const float* l1w = (const float*)d_in[8];
    const float* l2w = (const float*)d_in[9];
    const float* l2b = (const float*)d_in[10];
    const float* lw  = (const float*)d_in[11];
    const float* lb  = (const float*)d_in[12];

    const int N = in_sizes[0] / 128;   // 40000
    const int E = in_sizes[2];         // 640000

    float* hbuf = (float*)d_ws;                           // N*128 f32
    float* agg  = hbuf + (size_t)N * 128;                 // N*128 f32
    _Float16* w1f = (_Float16*)(agg + (size_t)N * 128);   // 8192
    _Float16* w2f = w1f + 8192;
    _Float16* l1f = w2f + 16384;
    _Float16* l2f = l1f + 16384;
    _Float16* lwf = l2f + 16384;

    const int nb = (N + 63) / 64;

    prep_kernel<<<288, 256, 0, stream>>>(w1, w2, l1w, l2w, lw,
                                         w1f, w2f, l1f, l2f, lwf);
    hipMemsetAsync(agg, 0, (size_t)N * 128 * sizeof(float), stream);
    h_gemm_kernel<<<nb, 256, 0, stream>>>(x, l1f, hbuf, N);
    edge_kernel<<<(E + 63) / 64, 256, 0, stream>>>(ea, ew, ei, ei + E,
                                                   w1f, w2f, b1, b2, hbuf, agg, E);
    fused_out_kernel<<<nb, 256, 0, stream>>>(agg, l2f, l2b, lwf, lb, (float*)d_out, N);
}

// Round 5
// 571.090 us; speedup vs baseline: 8.0412x; 1.0934x over previous
//
#include <hip/hip_runtime.h>
#include <math.h>

#define LN2F 0.69314718055994531f

typedef _Float16 v8hf __attribute__((ext_vector_type(8)));
typedef float    v4f  __attribute__((ext_vector_type(4)));

// fast shifted-softplus via v_exp_f32/v_log_f32 (~10 VALU instr vs ~50 libm).
// abs err ~2e-6 -- negligible vs the ~1e-3 f16 filter-quantization budget.
// (log(1+e) at e<<1 loses relative precision but abs err stays ~6e-8.)
__device__ __forceinline__ float ssp_fast(float x) {
    float e = __expf(-fabsf(x));
    return fmaxf(x, 0.f) + __logf(1.f + e) - LN2F;
}

// ---------------------------------------------------------------------------
// Prep: weights -> f16, MFMA-B-fragment order.
//   frag[((nt*KS+ks)*64 + lane)*8 + i] = W[nt*16+(lane&15)][ks*32+(lane>>4)*8+i]
// w1: 128x50 (K padded 64, KS=2); others 128x128 (KS=4).
// ---------------------------------------------------------------------------
__global__ __launch_bounds__(256)
void prep_kernel(const float* __restrict__ w1, const float* __restrict__ w2,
                 const float* __restrict__ l1w, const float* __restrict__ l2w,
                 const float* __restrict__ lw,
                 _Float16* __restrict__ w1f, _Float16* __restrict__ w2f,
                 _Float16* __restrict__ l1f, _Float16* __restrict__ l2f,
                 _Float16* __restrict__ lwf)
{
    int idx = blockIdx.x * 256 + threadIdx.x;
    if (idx < 8192) {  // w1f
        int i = idx & 7, lane = (idx >> 3) & 63, ks = (idx >> 9) & 1, nt = idx >> 10;
        int r = nt * 16 + (lane & 15);
        int k = ks * 32 + (lane >> 4) * 8 + i;
        w1f[idx] = (k < 50) ? (_Float16)w1[r * 50 + k] : (_Float16)0.f;
        return;
    }
    int o = idx - 8192;
    if (o >= 4 * 16384) return;
    int which = o >> 14;
    int p = o & 16383;
    int i = p & 7, lane = (p >> 3) & 63, ks = (p >> 9) & 3, nt = p >> 11;
    int r = nt * 16 + (lane & 15);
    int k = ks * 32 + (lane >> 4) * 8 + i;
    const float* src = (which == 0) ? w2 : (which == 1) ? l1w : (which == 2) ? l2w : lw;
    _Float16* dst   = (which == 0) ? w2f : (which == 1) ? l1f : (which == 2) ? l2f : lwf;
    dst[p] = (_Float16)src[r * 128 + k];
}

// ---------------------------------------------------------------------------
// h = X @ W^T (no bias/act). f16 MFMA, B-frags from global. 4 waves x 16 rows.
// ---------------------------------------------------------------------------
__global__ __launch_bounds__(256)
void h_gemm_kernel(const float* __restrict__ X, const _Float16* __restrict__ Wf,
                   float* __restrict__ Y, int M)
{
    const int tid = threadIdx.x, lane = tid & 63, wv = tid >> 6;
    const int l15 = lane & 15, quad = lane >> 4;
    const int mb = blockIdx.x * 64 + wv * 16;

    const int mA = (mb + l15 < M) ? (mb + l15) : (M - 1);
    v8hf a[4];
    #pragma unroll
    for (int ks = 0; ks < 4; ++ks) {
        const float4* xp = (const float4*)&X[(size_t)mA * 128 + ks * 32 + quad * 8];
        float4 x0 = xp[0], x1 = xp[1];
        v8hf t = {(_Float16)x0.x, (_Float16)x0.y, (_Float16)x0.z, (_Float16)x0.w,
                  (_Float16)x1.x, (_Float16)x1.y, (_Float16)x1.z, (_Float16)x1.w};
        a[ks] = t;
    }
    #pragma unroll
    for (int nt = 0; nt < 8; ++nt) {
        v4f acc = {0.f, 0.f, 0.f, 0.f};
        #pragma unroll
        for (int ks = 0; ks < 4; ++ks) {
            const v8hf b = *(const v8hf*)&Wf[((nt * 4 + ks) * 64 + lane) * 8];
            acc = __builtin_amdgcn_mfma_f32_16x16x32_f16(a[ks], b, acc, 0, 0, 0);
        }
        const int col = nt * 16 + l15;
        #pragma unroll
        for (int r = 0; r < 4; ++r) {
            int row = mb + quad * 4 + r;
            if (row < M) Y[(size_t)row * 128 + col] = acc[r];
        }
    }
}

// ---------------------------------------------------------------------------
// Fused tail: out = ssp(agg @ l2^T + l2b) @ lw^T + lb.
// s goes D-layout -> LDS -> A-layout; rows are wave-private (no barrier).
// ---------------------------------------------------------------------------
__global__ __launch_bounds__(256)
void fused_out_kernel(const float* __restrict__ agg, const _Float16* __restrict__ l2f,
                      const float* __restrict__ l2b, const _Float16* __restrict__ lwf,
                      const float* __restrict__ lb, float* __restrict__ out, int M)
{
    __shared__ __align__(16) _Float16 Sh[64 * 138];
    const int tid = threadIdx.x, lane = tid & 63, wv = tid >> 6;
    const int l15 = lane & 15, quad = lane >> 4;
    const int m0 = wv * 16;
    const int gbase = blockIdx.x * 64;

    const int mA = (gbase + m0 + l15 < M) ? (gbase + m0 + l15) : (M - 1);
    v8hf a[4];
    #pragma unroll
    for (int ks = 0; ks < 4; ++ks) {
        const float4* xp = (const float4*)&agg[(size_t)mA * 128 + ks * 32 + quad * 8];
        float4 x0 = xp[0], x1 = xp[1];
        v8hf t = {(_Float16)x0.x, (_Float16)x0.y, (_Float16)x0.z, (_Float16)x0.w,
                  (_Float16)x1.x, (_Float16)x1.y, (_Float16)x1.z, (_Float16)x1.w};
        a[ks] = t;
    }
    #pragma unroll
    for (int nt = 0; nt < 8; ++nt) {
        v4f acc = {0.f, 0.f, 0.f, 0.f};
        #pragma unroll
        for (int ks = 0; ks < 4; ++ks) {
            const v8hf b = *(const v8hf*)&l2f[((nt * 4 + ks) * 64 + lane) * 8];
            acc = __builtin_amdgcn_mfma_f32_16x16x32_f16(a[ks], b, acc, 0, 0, 0);
        }
        const float bj = l2b[nt * 16 + l15];
        #pragma unroll
        for (int r = 0; r < 4; ++r)
            Sh[(m0 + quad * 4 + r) * 138 + nt * 16 + l15] =
                (_Float16)ssp_fast(acc[r] + bj);
    }
    v8hf ua[4];
    #pragma unroll
    for (int ks = 0; ks < 4; ++ks)
        ua[ks] = *(const v8hf*)&Sh[(m0 + l15) * 138 + ks * 32 + quad * 8];

    #pragma unroll
    for (int nt = 0; nt < 8; ++nt) {
        v4f acc = {0.f, 0.f, 0.f, 0.f};
        #pragma unroll
        for (int ks = 0; ks < 4; ++ks) {
            const v8hf b = *(const v8hf*)&lwf[((nt * 4 + ks) * 64 + lane) * 8];
            acc = __builtin_amdgcn_mfma_f32_16x16x32_f16(ua[ks], b, acc, 0, 0, 0);
        }
        const int col = nt * 16 + l15;
        const float bj = lb[col];
        #pragma unroll
        for (int r = 0; r < 4; ++r) {
            int row = gbase + m0 + quad * 4 + r;
            if (row < M) out[(size_t)row * 128 + col] = acc[r] + bj;
        }
    }
}

// ---------------------------------------------------------------------------
// Fused edge kernel (round-3 proven structure + fast ssp).
// 64 edges/block, 256 threads (4 waves x 16 edges).
//   stage1: u = ssp(attr @ W1^T + b1)        (MFMA K=64; B-frags from global)
//   stage2: Wf = (u @ W2^T + b2) * C         (MFMA K=128, no LDS round-trip)
//   epilogue in D-layout: 16 consecutive lanes cover 16 consecutive cols of
//   ONE edge-row -> 64B-coalesced gather AND atomics
//   (round-2 lesson: lane-scattered f32 atomics cost 32B HBM/atomic = 8x).
// NOTE round-4 lesson: the barrier-free + launch_bounds(256,8) restructure
// failed the replay tripwire (post-timing divergence) AND regressed to 722us
// (VGPR cap 64 -> scratch spills). Keeping the barriered structure.
// LDS strides 74/138 f16 (odd word counts -> conflict-free b128 reads).
// ---------------------------------------------------------------------------
__global__ __launch_bounds__(256, 5)
void edge_kernel(const float* __restrict__ attr,  // E x 50
                 const float* __restrict__ ew,    // E
                 const int* __restrict__ srcI,
                 const int* __restrict__ dstI,
                 const _Float16* __restrict__ w1f,
                 const _Float16* __restrict__ w2f,
                 const float* __restrict__ b1,
                 const float* __restrict__ b2,
                 const float* __restrict__ h,     // N x 128
                 float* __restrict__ agg,         // N x 128 (zeroed)
                 int E)
{
    __shared__ __align__(16) _Float16 Ah[64 * 74];
    __shared__ __align__(16) _Float16 Uh[64 * 138];
    __shared__ float b1S[128], b2S[128], Cs[64];
    __shared__ int sS[64], dS[64];

    const int tid = threadIdx.x;
    const int e_base = blockIdx.x * 64;

    for (int idx = tid; idx < 64 * 64; idx += 256) {
        int r = idx >> 6, g = idx & 63;
        int e = e_base + r;
        float v = (g < 50 && e < E) ? attr[(size_t)e * 50 + g] : 0.f;
        Ah[r * 74 + g] = (_Float16)v;
    }
    if (tid < 128) { b1S[tid] = b1[tid]; b2S[tid] = b2[tid]; }
    if (tid < 64) {
        int e = e_base + tid;
        if (e < E) {
            Cs[tid] = 0.5f * (cosf(ew[e] * 0.31415926535897932f) + 1.f);
            sS[tid] = srcI[e]; dS[tid] = dstI[e];
        } else { Cs[tid] = 0.f; sS[tid] = 0; dS[tid] = 0; }
    }
    __syncthreads();

    const int lane = tid & 63, wv = tid >> 6;
    const int m0 = wv * 16, l15 = lane & 15, quad = lane >> 4;

    // ---- stage 1 ----
    const v8hf a0 = *(const v8hf*)&Ah[(m0 + l15) * 74 + quad * 8];
    const v8hf a1 = *(const v8hf*)&Ah[(m0 + l15) * 74 + 32 + quad * 8];
    #pragma unroll
    for (int nt = 0; nt < 8; ++nt) {
        v4f acc = {0.f, 0.f, 0.f, 0.f};
        const v8hf bA = *(const v8hf*)&w1f[((nt * 2 + 0) * 64 + lane) * 8];
        const v8hf bB = *(const v8hf*)&w1f[((nt * 2 + 1) * 64 + lane) * 8];
        acc = __builtin_amdgcn_mfma_f32_16x16x32_f16(a0, bA, acc, 0, 0, 0);
        acc = __builtin_amdgcn_mfma_f32_16x16x32_f16(a1, bB, acc, 0, 0, 0);
        const float bj = b1S[nt * 16 + l15];
        #pragma unroll
        for (int r = 0; r < 4; ++r)
            Uh[(m0 + quad * 4 + r) * 138 + nt * 16 + l15] =
                (_Float16)ssp_fast(acc[r] + bj);
    }

    // ---- stage 2 + D-layout epilogue (wave-private LDS rows) ----
    v8hf ua[4];
    #pragma unroll
    for (int ks = 0; ks < 4; ++ks)
        ua[ks] = *(const v8hf*)&Uh[(m0 + l15) * 138 + ks * 32 + quad * 8];

    float cC[4]; const float* hrow[4]; float* arow[4]; bool val[4];
    #pragma unroll
    for (int r = 0; r < 4; ++r) {
        int el = m0 + quad * 4 + r;
        cC[r] = Cs[el];
        hrow[r] = h + (size_t)sS[el] * 128;
        arow[r] = agg + (size_t)dS[el] * 128;
        val[r] = (e_base + el) < E;
    }

    #pragma unroll
    for (int nt = 0; nt < 8; ++nt) {
        v4f acc = {0.f, 0.f, 0.f, 0.f};
        #pragma unroll
        for (int ks = 0; ks < 4; ++ks) {
            const v8hf b = *(const v8hf*)&w2f[((nt * 4 + ks) * 64 + lane) * 8];
            acc = __builtin_amdgcn_mfma_f32_16x16x32_f16(ua[ks], b, acc, 0, 0, 0);
        }
        const int col = nt * 16 + l15;
        const float bj = b2S[col];
        #pragma unroll
        for (int r = 0; r < 4; ++r) {
            if (val[r]) {
                float wf = (acc[r] + bj) * cC[r];
                atomicAdd(&arow[r][col], wf * hrow[r][col]);
            }
        }
    }
}

extern "C" void kernel_launch(void* const* d_in, const int* in_sizes, int n_in,
                              void* d_out, int out_size, void* d_ws, size_t ws_size,
                              hipStream_t stream)
{
    const float* x   = (const float*)d_in[0];
    const int*   ei  = (const int*)  d_in[1];
    const float* ew  = (const float*)d_in[2];
    const float* ea  = (const float*)d_in[3];
    const float* w1  = (const float*)d_in[4];
    const float* b1  = (const float*)d_in[5];
    const float* w2  = (const float*)d_in[6];
    const float* b2  = (const float*)d_in[7];
    const float* l1w = (const float*)d_in[8];
    const float* l2w = (const float*)d_in[9];
    const float* l2b = (const float*)d_in[10];
    const float* lw  = (const float*)d_in[11];
    const float* lb  = (const float*)d_in[12];

    const int N = in_sizes[0] / 128;   // 40000
    const int E = in_sizes[2];         // 640000

    float* hbuf = (float*)d_ws;                           // N*128 f32
    float* agg  = hbuf + (size_t)N * 128;                 // N*128 f32
    _Float16* w1f = (_Float16*)(agg + (size_t)N * 128);   // 8192
    _Float16* w2f = w1f + 8192;
    _Float16* l1f = w2f + 16384;
    _Float16* l2f = l1f + 16384;
    _Float16* lwf = l2f + 16384;

    const int nb = (N + 63) / 64;

    prep_kernel<<<288, 256, 0, stream>>>(w1, w2, l1w, l2w, lw,
                                         w1f, w2f, l1f, l2f, lwf);
    hipMemsetAsync(agg, 0, (size_t)N * 128 * sizeof(float), stream);
    h_gemm_kernel<<<nb, 256, 0, stream>>>(x, l1f, hbuf, N);
    edge_kernel<<<(E + 63) / 64, 256, 0, stream>>>(ea, ew, ei, ei + E,
                                                   w1f, w2f, b1, b2, hbuf, agg, E);
    fused_out_kernel<<<nb, 256, 0, stream>>>(agg, l2f, l2b, lwf, lb, (float*)d_out, N);
}

// Round 6
// 544.062 us; speedup vs baseline: 8.4406x; 1.0497x over previous
//
#include <hip/hip_runtime.h>
#include <math.h>

#define LN2F 0.69314718055994531f

typedef _Float16 v8hf __attribute__((ext_vector_type(8)));
typedef float    v4f  __attribute__((ext_vector_type(4)));

// fast shifted-softplus via v_exp_f32/v_log_f32 (~10 VALU instr vs ~50 libm).
// abs err ~2e-6 -- negligible vs the ~1e-3 f16 filter-quantization budget.
__device__ __forceinline__ float ssp_fast(float x) {
    float e = __expf(-fabsf(x));
    return fmaxf(x, 0.f) + __logf(1.f + e) - LN2F;
}

// ---------------------------------------------------------------------------
// Prep: weights -> f16, MFMA-B-fragment order.
//   frag[((nt*KS+ks)*64 + lane)*8 + i] = W[nt*16+(lane&15)][ks*32+(lane>>4)*8+i]
// w1: 128x50 (K padded 64, KS=2); others 128x128 (KS=4).
// ---------------------------------------------------------------------------
__global__ __launch_bounds__(256)
void prep_kernel(const float* __restrict__ w1, const float* __restrict__ w2,
                 const float* __restrict__ l1w, const float* __restrict__ l2w,
                 const float* __restrict__ lw,
                 _Float16* __restrict__ w1f, _Float16* __restrict__ w2f,
                 _Float16* __restrict__ l1f, _Float16* __restrict__ l2f,
                 _Float16* __restrict__ lwf)
{
    int idx = blockIdx.x * 256 + threadIdx.x;
    if (idx < 8192) {  // w1f
        int i = idx & 7, lane = (idx >> 3) & 63, ks = (idx >> 9) & 1, nt = idx >> 10;
        int r = nt * 16 + (lane & 15);
        int k = ks * 32 + (lane >> 4) * 8 + i;
        w1f[idx] = (k < 50) ? (_Float16)w1[r * 50 + k] : (_Float16)0.f;
        return;
    }
    int o = idx - 8192;
    if (o >= 4 * 16384) return;
    int which = o >> 14;
    int p = o & 16383;
    int i = p & 7, lane = (p >> 3) & 63, ks = (p >> 9) & 3, nt = p >> 11;
    int r = nt * 16 + (lane & 15);
    int k = ks * 32 + (lane >> 4) * 8 + i;
    const float* src = (which == 0) ? w2 : (which == 1) ? l1w : (which == 2) ? l2w : lw;
    _Float16* dst   = (which == 0) ? w2f : (which == 1) ? l1f : (which == 2) ? l2f : lwf;
    dst[p] = (_Float16)src[r * 128 + k];
}

// ---------------------------------------------------------------------------
// h = X @ W^T (no bias/act). f16 MFMA, B-frags from global. 4 waves x 16 rows.
// ---------------------------------------------------------------------------
__global__ __launch_bounds__(256)
void h_gemm_kernel(const float* __restrict__ X, const _Float16* __restrict__ Wf,
                   float* __restrict__ Y, int M)
{
    const int tid = threadIdx.x, lane = tid & 63, wv = tid >> 6;
    const int l15 = lane & 15, quad = lane >> 4;
    const int mb = blockIdx.x * 64 + wv * 16;

    const int mA = (mb + l15 < M) ? (mb + l15) : (M - 1);
    v8hf a[4];
    #pragma unroll
    for (int ks = 0; ks < 4; ++ks) {
        const float4* xp = (const float4*)&X[(size_t)mA * 128 + ks * 32 + quad * 8];
        float4 x0 = xp[0], x1 = xp[1];
        v8hf t = {(_Float16)x0.x, (_Float16)x0.y, (_Float16)x0.z, (_Float16)x0.w,
                  (_Float16)x1.x, (_Float16)x1.y, (_Float16)x1.z, (_Float16)x1.w};
        a[ks] = t;
    }
    #pragma unroll
    for (int nt = 0; nt < 8; ++nt) {
        v4f acc = {0.f, 0.f, 0.f, 0.f};
        #pragma unroll
        for (int ks = 0; ks < 4; ++ks) {
            const v8hf b = *(const v8hf*)&Wf[((nt * 4 + ks) * 64 + lane) * 8];
            acc = __builtin_amdgcn_mfma_f32_16x16x32_f16(a[ks], b, acc, 0, 0, 0);
        }
        const int col = nt * 16 + l15;
        #pragma unroll
        for (int r = 0; r < 4; ++r) {
            int row = mb + quad * 4 + r;
            if (row < M) Y[(size_t)row * 128 + col] = acc[r];
        }
    }
}

// ---------------------------------------------------------------------------
// Fused tail: out = ssp(agg @ l2^T + l2b) @ lw^T + lb.
// s goes D-layout -> LDS -> A-layout; rows are wave-private (no barrier).
// ---------------------------------------------------------------------------
__global__ __launch_bounds__(256)
void fused_out_kernel(const float* __restrict__ agg, const _Float16* __restrict__ l2f,
                      const float* __restrict__ l2b, const _Float16* __restrict__ lwf,
                      const float* __restrict__ lb, float* __restrict__ out, int M)
{
    __shared__ __align__(16) _Float16 Sh[64 * 138];
    const int tid = threadIdx.x, lane = tid & 63, wv = tid >> 6;
    const int l15 = lane & 15, quad = lane >> 4;
    const int m0 = wv * 16;
    const int gbase = blockIdx.x * 64;

    const int mA = (gbase + m0 + l15 < M) ? (gbase + m0 + l15) : (M - 1);
    v8hf a[4];
    #pragma unroll
    for (int ks = 0; ks < 4; ++ks) {
        const float4* xp = (const float4*)&agg[(size_t)mA * 128 + ks * 32 + quad * 8];
        float4 x0 = xp[0], x1 = xp[1];
        v8hf t = {(_Float16)x0.x, (_Float16)x0.y, (_Float16)x0.z, (_Float16)x0.w,
                  (_Float16)x1.x, (_Float16)x1.y, (_Float16)x1.z, (_Float16)x1.w};
        a[ks] = t;
    }
    #pragma unroll
    for (int nt = 0; nt < 8; ++nt) {
        v4f acc = {0.f, 0.f, 0.f, 0.f};
        #pragma unroll
        for (int ks = 0; ks < 4; ++ks) {
            const v8hf b = *(const v8hf*)&l2f[((nt * 4 + ks) * 64 + lane) * 8];
            acc = __builtin_amdgcn_mfma_f32_16x16x32_f16(a[ks], b, acc, 0, 0, 0);
        }
        const float bj = l2b[nt * 16 + l15];
        #pragma unroll
        for (int r = 0; r < 4; ++r)
            Sh[(m0 + quad * 4 + r) * 138 + nt * 16 + l15] =
                (_Float16)ssp_fast(acc[r] + bj);
    }
    v8hf ua[4];
    #pragma unroll
    for (int ks = 0; ks < 4; ++ks)
        ua[ks] = *(const v8hf*)&Sh[(m0 + l15) * 138 + ks * 32 + quad * 8];

    #pragma unroll
    for (int nt = 0; nt < 8; ++nt) {
        v4f acc = {0.f, 0.f, 0.f, 0.f};
        #pragma unroll
        for (int ks = 0; ks < 4; ++ks) {
            const v8hf b = *(const v8hf*)&lwf[((nt * 4 + ks) * 64 + lane) * 8];
            acc = __builtin_amdgcn_mfma_f32_16x16x32_f16(ua[ks], b, acc, 0, 0, 0);
        }
        const int col = nt * 16 + l15;
        const float bj = lb[col];
        #pragma unroll
        for (int r = 0; r < 4; ++r) {
            int row = gbase + m0 + quad * 4 + r;
            if (row < M) out[(size_t)row * 128 + col] = acc[r] + bj;
        }
    }
}

// ---------------------------------------------------------------------------
// Fused edge kernel (r3/r5 proven structure + register h-prefetch).
// 64 edges/block, 256 threads (4 waves x 16 edges).
//   - per-lane metadata (ew/src/dst) read direct from global (L1 broadcast);
//     their LDS staging is gone.
//   - ALL 32 h[src] gather values prefetched into registers right after the
//     staging barrier -> LLC latency overlaps stage-1+2 MFMA instead of being
//     exposed in the epilogue (r5 counters: all pipes <21%, latency-bound).
//     VGPR headroom: 44 used, 102 available at the 5-block LDS cap.
//   - attr staged in A-fragment order (8KB, b128-contiguous reads).
//   epilogue in D-layout: 16 consecutive lanes = 16 consecutive cols of ONE
//   edge-row -> 64B-coalesced atomics (r2 lesson: anything else is 8x HBM).
// NOTE r4 lesson: barrier-free + launch_bounds(256,8) diverged under replay;
// keeping the barriered structure and (256,5).
// ---------------------------------------------------------------------------
__global__ __launch_bounds__(256, 5)
void edge_kernel(const float* __restrict__ attr,  // E x 50
                 const float* __restrict__ ew,    // E
                 const int* __restrict__ srcI,
                 const int* __restrict__ dstI,
                 const _Float16* __restrict__ w1f,
                 const _Float16* __restrict__ w2f,
                 const float* __restrict__ b1,
                 const float* __restrict__ b2,
                 const float* __restrict__ h,     // N x 128
                 float* __restrict__ agg,         // N x 128 (zeroed)
                 int E)
{
    __shared__ __align__(16) _Float16 Af[64 * 64];   // A-fragment-packed attr
    __shared__ __align__(16) _Float16 Uh[64 * 138];

    const int tid = threadIdx.x;
    const int e_base = blockIdx.x * 64;
    const int lane = tid & 63, wv = tid >> 6;
    const int m0 = wv * 16, l15 = lane & 15, quad = lane >> 4;

    // ---- per-lane edge metadata (direct global; 16-lane groups share -> L1) ----
    float cC[4]; const float* hrow[4]; float* arow[4]; bool val[4];
    #pragma unroll
    for (int r = 0; r < 4; ++r) {
        int eg = e_base + m0 + quad * 4 + r;
        val[r] = eg < E;
        int e = val[r] ? eg : (E - 1);
        cC[r] = 0.5f * (__cosf(ew[e] * 0.31415926535897932f) + 1.f);
        hrow[r] = h + (size_t)srcI[e] * 128;
        arow[r] = agg + (size_t)dstI[e] * 128;
    }

    // ---- stage attr -> LDS in A-fragment order ----
    // (r,g) -> Af[(((r>>4)*2 + (g>>5))*64 + ((g&31)>>3)*16 + (r&15))*8 + (g&7)]
    for (int idx = tid; idx < 4096; idx += 256) {
        int r = idx >> 6, g = idx & 63;
        int e = e_base + r;
        float v = (g < 50 && e < E) ? attr[(size_t)e * 50 + g] : 0.f;
        Af[((((r >> 4) * 2 + (g >> 5)) * 64) + (((g & 31) >> 3) * 16) + (r & 15)) * 8
           + (g & 7)] = (_Float16)v;
    }
    __syncthreads();

    // ---- h-gather prefetch: issue all 32 loads NOW; consumed in epilogue.
    // Latency hides behind both MFMA stages. 32 VGPRs, within budget.
    float hv[8][4];
    #pragma unroll
    for (int nt = 0; nt < 8; ++nt)
        #pragma unroll
        for (int r = 0; r < 4; ++r)
            hv[nt][r] = hrow[r][nt * 16 + l15];

    // ---- stage 1: u = ssp(attr @ W1^T + b1) -> Uh (wave-private rows) ----
    const v8hf a0 = *(const v8hf*)&Af[((wv * 2 + 0) * 64 + lane) * 8];
    const v8hf a1 = *(const v8hf*)&Af[((wv * 2 + 1) * 64 + lane) * 8];
    #pragma unroll
    for (int nt = 0; nt < 8; ++nt) {
        v4f acc = {0.f, 0.f, 0.f, 0.f};
        const v8hf bA = *(const v8hf*)&w1f[((nt * 2 + 0) * 64 + lane) * 8];
        const v8hf bB = *(const v8hf*)&w1f[((nt * 2 + 1) * 64 + lane) * 8];
        acc = __builtin_amdgcn_mfma_f32_16x16x32_f16(a0, bA, acc, 0, 0, 0);
        acc = __builtin_amdgcn_mfma_f32_16x16x32_f16(a1, bB, acc, 0, 0, 0);
        const float bj = b1[nt * 16 + l15];
        #pragma unroll
        for (int r = 0; r < 4; ++r)
            Uh[(m0 + quad * 4 + r) * 138 + nt * 16 + l15] =
                (_Float16)ssp_fast(acc[r] + bj);
    }

    // ---- stage 2 + D-layout epilogue (wave-private LDS rows) ----
    v8hf ua[4];
    #pragma unroll
    for (int ks = 0; ks < 4; ++ks)
        ua[ks] = *(const v8hf*)&Uh[(m0 + l15) * 138 + ks * 32 + quad * 8];

    #pragma unroll
    for (int nt = 0; nt < 8; ++nt) {
        v4f acc = {0.f, 0.f, 0.f, 0.f};
        #pragma unroll
        for (int ks = 0; ks < 4; ++ks) {
            const v8hf b = *(const v8hf*)&w2f[((nt * 4 + ks) * 64 + lane) * 8];
            acc = __builtin_amdgcn_mfma_f32_16x16x32_f16(ua[ks], b, acc, 0, 0, 0);
        }
        const int col = nt * 16 + l15;
        const float bj = b2[col];
        #pragma unroll
        for (int r = 0; r < 4; ++r) {
            if (val[r]) {
                float wf = (acc[r] + bj) * cC[r];
                atomicAdd(&arow[r][col], wf * hv[nt][r]);
            }
        }
    }
}

extern "C" void kernel_launch(void* const* d_in, const int* in_sizes, int n_in,
                              void* d_out, int out_size, void* d_ws, size_t ws_size,
                              hipStream_t stream)
{
    const float* x   = (const float*)d_in[0];
    const int*   ei  = (const int*)  d_in[1];
    const float* ew  = (const float*)d_in[2];
    const float* ea  = (const float*)d_in[3];
    const float* w1  = (const float*)d_in[4];
    const float* b1  = (const float*)d_in[5];
    const float* w2  = (const float*)d_in[6];
    const float* b2  = (const float*)d_in[7];
    const float* l1w = (const float*)d_in[8];
    const float* l2w = (const float*)d_in[9];
    const float* l2b = (const float*)d_in[10];
    const float* lw  = (const float*)d_in[11];
    const float* lb  = (const float*)d_in[12];

    const int N = in_sizes[0] / 128;   // 40000
    const int E = in_sizes[2];         // 640000

    float* hbuf = (float*)d_ws;                           // N*128 f32
    float* agg  = hbuf + (size_t)N * 128;                 // N*128 f32
    _Float16* w1f = (_Float16*)(agg + (size_t)N * 128);   // 8192
    _Float16* w2f = w1f + 8192;
    _Float16* l1f = w2f + 16384;
    _Float16* l2f = l1f + 16384;
    _Float16* lwf = l2f + 16384;

    const int nb = (N + 63) / 64;

    prep_kernel<<<288, 256, 0, stream>>>(w1, w2, l1w, l2w, lw,
                                         w1f, w2f, l1f, l2f, lwf);
    hipMemsetAsync(agg, 0, (size_t)N * 128 * sizeof(float), stream);
    h_gemm_kernel<<<nb, 256, 0, stream>>>(x, l1f, hbuf, N);
    edge_kernel<<<(E + 63) / 64, 256, 0, stream>>>(ea, ew, ei, ei + E,
                                                   w1f, w2f, b1, b2, hbuf, agg, E);
    fused_out_kernel<<<nb, 256, 0, stream>>>(agg, l2f, l2b, lwf, lb, (float*)d_out, N);
}